// Round 2
// baseline (94.725 us; speedup 1.0000x reference)
//
#include <hip/hip_runtime.h>
#include <hip/hip_bf16.h>

// N=8192 rows, D=128. loss = mean(-log(exp(sims_ii)) + 0.5*(log(den_i)+log(den_j)))
// sims = (A @ T^T) * exp(temp); den = row/col sums of exp(sims) with diag zeroed.
//
// ws layout (bytes):
//   [0,       2 MiB)  A bf16, XOR-swizzled chunks   (ushort[8192][128])
//   [2 MiB,   4 MiB)  T bf16, XOR-swizzled chunks
//   [4 MiB,   5 MiB)  den_i partials float[8192][32]   (slot = by*4+wc)
//   [5 MiB,   9 MiB)  den_j partials float[8192][128]  (slot = s*2+wr)
//   [9 MiB, +32 KiB)  per-row loss float[8192]

typedef __attribute__((ext_vector_type(8))) __bf16 bf16x8;
typedef __attribute__((ext_vector_type(4))) float  f32x4;

#define GLD16(g, l) __builtin_amdgcn_global_load_lds(                         \
    (const __attribute__((address_space(1))) unsigned int*)(const void*)(g),  \
    (__attribute__((address_space(3))) unsigned int*)(void*)(l), 16, 0, 0)

__device__ __forceinline__ ushort f2bf(float f) {
    union { float f; unsigned u; } v; v.f = f;
    unsigned r = v.u + 0x7fffu + ((v.u >> 16) & 1u);   // RNE (finite inputs)
    return (ushort)(r >> 16);
}

// ---------------------------------------------------------------- kernel 1
// One thread = one 8-element chunk. Swizzle: chunk c of row r lands at c^(r&7)
// (byte ^= (r&7)<<4), so GEMM stages linearly and ds_reads with the same XOR.
__global__ void convert_swizzle(const float* __restrict__ a,
                                const float* __restrict__ t,
                                ushort* __restrict__ oa,
                                ushort* __restrict__ ot) {
    int idx = blockIdx.x * 256 + threadIdx.x;          // 0 .. 262143
    const float* src = (idx >> 17) ? t : a;
    ushort*      dst = (idx >> 17) ? ot : oa;
    int loc = idx & 131071;
    int r = loc >> 4;
    int c = loc & 15;
    const float4* s4 = reinterpret_cast<const float4*>(src + r * 128 + c * 8);
    float4 f0 = s4[0], f1 = s4[1];
    uint4 o;
    o.x = f2bf(f0.x) | ((unsigned)f2bf(f0.y) << 16);
    o.y = f2bf(f0.z) | ((unsigned)f2bf(f0.w) << 16);
    o.z = f2bf(f1.x) | ((unsigned)f2bf(f1.y) << 16);
    o.w = f2bf(f1.z) | ((unsigned)f2bf(f1.w) << 16);
    *reinterpret_cast<uint4*>(dst + r * 128 + ((c ^ (r & 7)) << 3)) = o;
}

// ---------------------------------------------------------------- kernel 2
// Strip GEMM: block = 128 A-rows (s) x 1024 T-cols (by), 8 j-tiles of 128.
// 8 waves (wr in {0,1} x wc in {0..3}); wave tile 64 rows x 32 cols.
// A-frags resident in registers; B double-buffered in LDS, staged one tile
// ahead (2-phase). Row sums accumulate in registers across the j-loop.
__global__ void __launch_bounds__(512)
gemm_exp(const ushort* __restrict__ Ab, const ushort* __restrict__ Tb,
         const float* __restrict__ temps,
         float* __restrict__ Pi, float* __restrict__ Pj) {
    __shared__ ushort lds[2][16384];                   // 2 x 32 KiB
    const int s = blockIdx.x, by = blockIdx.y;
    const int tid = threadIdx.x;
    const int wave = tid >> 6, lane = tid & 63;
    const int wr = wave >> 2, wc = wave & 3;
    const int krow = lane >> 4, lcol = lane & 15;
    const float sc = __expf(temps[0]);

    // ---- stage A strip (32 KiB, pre-swizzled, contiguous) into lds[0]
    const ushort* gA = Ab + s * 16384;
#pragma unroll
    for (int i = 0; i < 4; ++i) {
        int c = wave * 256 + i * 64;                   // 16B-chunk index, wave-uniform
        GLD16(gA + (c + lane) * 8, &lds[0][c * 8]);
    }
    __syncthreads();

    // ---- A fragments to registers (64 VGPR), then free lds[0] for B
    bf16x8 af[4][4];
#pragma unroll
    for (int m = 0; m < 4; ++m) {
        int ra = wr * 64 + m * 16 + lcol;
#pragma unroll
        for (int kk = 0; kk < 4; ++kk) {
            int k0 = kk * 32 + krow * 8;
            af[m][kk] = *reinterpret_cast<const bf16x8*>(
                &lds[0][ra * 128 + (k0 ^ ((ra & 7) << 3))]);
        }
    }
    __syncthreads();                                   // all waves done reading A

    float rsum[4][4] = {};                             // [m][j] across all j-tiles
    const ushort* gB = Tb + by * 131072;               // this block's 8 B tiles

    // ---- prologue: stage B tile 0 into lds[0]
#pragma unroll
    for (int i = 0; i < 4; ++i) {
        int c = wave * 256 + i * 64;
        GLD16(gB + (c + lane) * 8, &lds[0][c * 8]);
    }
    __syncthreads();

#pragma unroll
    for (int t = 0; t < 8; ++t) {
        // issue next tile's stage FIRST (lands during MFMA+epilogue)
        if (t < 7) {
            const ushort* g = gB + (t + 1) * 16384;
#pragma unroll
            for (int i = 0; i < 4; ++i) {
                int c = wave * 256 + i * 64;
                GLD16(g + (c + lane) * 8, &lds[(t + 1) & 1][c * 8]);
            }
        }

        f32x4 acc[4][2];
#pragma unroll
        for (int m = 0; m < 4; ++m)
#pragma unroll
            for (int n = 0; n < 2; ++n)
                acc[m][n] = (f32x4){0.f, 0.f, 0.f, 0.f};

#pragma unroll
        for (int kk = 0; kk < 4; ++kk) {
            int k0 = kk * 32 + krow * 8;
            int rb0 = wc * 32 + lcol;
            int rb1 = wc * 32 + 16 + lcol;
            bf16x8 b0 = *reinterpret_cast<const bf16x8*>(
                &lds[t & 1][rb0 * 128 + (k0 ^ ((rb0 & 7) << 3))]);
            bf16x8 b1 = *reinterpret_cast<const bf16x8*>(
                &lds[t & 1][rb1 * 128 + (k0 ^ ((rb1 & 7) << 3))]);
#pragma unroll
            for (int m = 0; m < 4; ++m) {
                acc[m][0] = __builtin_amdgcn_mfma_f32_16x16x32_bf16(af[m][kk], b0, acc[m][0], 0, 0, 0);
                acc[m][1] = __builtin_amdgcn_mfma_f32_16x16x32_bf16(af[m][kk], b1, acc[m][1], 0, 0, 0);
            }
        }

        // ---- epilogue: exp, row-sum accumulate (regs), col-sum write
        float csum[2] = {0.f, 0.f};
#pragma unroll
        for (int m = 0; m < 4; ++m)
#pragma unroll
            for (int n = 0; n < 2; ++n)
#pragma unroll
                for (int j = 0; j < 4; ++j) {
                    float v = __expf(acc[m][n][j] * sc);
                    rsum[m][j] += v;
                    csum[n] += v;
                }
#pragma unroll
        for (int n = 0; n < 2; ++n) {
            float v = csum[n];
            v += __shfl_xor(v, 16); v += __shfl_xor(v, 32);
            if (lane < 16) {
                int col = by * 1024 + t * 128 + wc * 32 + n * 16 + lane;
                Pj[col * 128 + s * 2 + wr] = v;
            }
        }
        __syncthreads();   // drains this wave's stage (vmcnt) + all waves' reads
    }

    // ---- row-sum partials: reduce over lcol, write Pi[row][by*4+wc]
#pragma unroll
    for (int m = 0; m < 4; ++m)
#pragma unroll
        for (int j = 0; j < 4; ++j) {
            float v = rsum[m][j];
            v += __shfl_xor(v, 1); v += __shfl_xor(v, 2);
            v += __shfl_xor(v, 4); v += __shfl_xor(v, 8);
            if (lcol == 0) {
                int row = s * 128 + wr * 64 + m * 16 + krow * 4 + j;
                Pi[row * 32 + by * 4 + wc] = v;
            }
        }
}

// ---------------------------------------------------------------- kernel 3
// One wave per row, 4 rows/block. All reads coalesced (partials transposed).
__global__ void finalize_rows(const float* __restrict__ a, const float* __restrict__ t,
                              const float* __restrict__ temps,
                              const float* __restrict__ Pi, const float* __restrict__ Pj,
                              float* __restrict__ loss) {
    const int r = blockIdx.x * 4 + (threadIdx.x >> 6);
    const int l = threadIdx.x & 63;
    const float sc = __expf(temps[0]);
    float deni = (l < 32) ? Pi[r * 32 + l] : 0.f;
    float denj = Pj[r * 128 + l] + Pj[r * 128 + 64 + l];
    float dotp = a[r * 128 + l] * t[r * 128 + l]
               + a[r * 128 + 64 + l] * t[r * 128 + 64 + l];
#pragma unroll
    for (int m = 1; m < 64; m <<= 1) {
        deni += __shfl_xor(deni, m);
        denj += __shfl_xor(denj, m);
        dotp += __shfl_xor(dotp, m);
    }
    if (l == 0) {
        float diag = __expf(sc * dotp);
        float di = fmaxf(deni - diag, 1e-20f);
        float dj = fmaxf(denj - diag, 1e-20f);
        loss[r] = -sc * dotp + 0.5f * (__logf(di) + __logf(dj));
    }
}

// ---------------------------------------------------------------- kernel 4
__global__ void reduce_loss(const float* __restrict__ loss, float* __restrict__ out) {
    __shared__ float wsum[16];
    const int tid = threadIdx.x;   // 1024
    float s = 0.f;
#pragma unroll
    for (int i = 0; i < 8; ++i) s += loss[tid + i * 1024];
#pragma unroll
    for (int m = 1; m < 64; m <<= 1) s += __shfl_xor(s, m);
    if ((tid & 63) == 0) wsum[tid >> 6] = s;
    __syncthreads();
    if (tid == 0) {
        float acc = 0.f;
#pragma unroll
        for (int w = 0; w < 16; ++w) acc += wsum[w];
        out[0] = acc * (1.0f / 8192.0f);
    }
}

extern "C" void kernel_launch(void* const* d_in, const int* in_sizes, int n_in,
                              void* d_out, int out_size, void* d_ws, size_t ws_size,
                              hipStream_t stream) {
    const float* a     = (const float*)d_in[0];
    const float* t     = (const float*)d_in[1];
    const float* temps = (const float*)d_in[2];
    float* out = (float*)d_out;

    char* ws = (char*)d_ws;
    ushort* Ab  = (ushort*)(ws);
    ushort* Tb  = (ushort*)(ws + (2u << 20));
    float*  Pi  = (float*)(ws + (4u << 20));
    float*  Pj  = (float*)(ws + (5u << 20));
    float*  los = (float*)(ws + (9u << 20));

    convert_swizzle<<<1024, 256, 0, stream>>>(a, t, Ab, Tb);
    gemm_exp<<<dim3(64, 8), 512, 0, stream>>>(Ab, Tb, temps, Pi, Pj);
    finalize_rows<<<2048, 256, 0, stream>>>(a, t, temps, Pi, Pj, los);
    reduce_loss<<<1, 1024, 0, stream>>>(los, out);
}

// Round 3
// 63.192 us; speedup vs baseline: 1.4990x; 1.4990x over previous
//
#include <hip/hip_runtime.h>
#include <hip/hip_bf16.h>

// N=8192, D=128. loss = mean(-log(exp(sims_ii)) + 0.5*(log(den_i)+log(den_j)))
// sims = (A @ T^T) * exp(temp); den = row/col sums of exp(sims), diag zeroed.
//
// ws layout (bytes):
//   [0,      2 MiB)  A bf16, FRAGMENT-MAJOR: [r16 0..511][kk 0..3][lane 0..63][8]
//   [2 MiB,  4 MiB)  T bf16, row-major XOR-swizzled chunks (ushort[8192][128])
//   [4 MiB,  8 MiB)  den_i partials float[8192][128]  (slot = bj*2+wc)
//   [8 MiB, 12 MiB)  den_j partials float[8192][128]  (slot = bi*2+wr)
//   [12 MiB,+32 KiB) per-row loss float[8192]

typedef __attribute__((ext_vector_type(8))) __bf16 bf16x8;
typedef __attribute__((ext_vector_type(4))) float  f32x4;

#define GLD16(g, l) __builtin_amdgcn_global_load_lds(                         \
    (const __attribute__((address_space(1))) unsigned int*)(const void*)(g),  \
    (__attribute__((address_space(3))) unsigned int*)(void*)(l), 16, 0, 0)

__device__ __forceinline__ ushort f2bf(float f) {
    union { float f; unsigned u; } v; v.f = f;
    unsigned r = v.u + 0x7fffu + ((v.u >> 16) & 1u);   // RNE (finite inputs)
    return (ushort)(r >> 16);
}

__device__ __forceinline__ float fast_exp2(float x) {
#if __has_builtin(__builtin_amdgcn_exp2f)
    return __builtin_amdgcn_exp2f(x);      // bare v_exp_f32
#else
    return __expf(x * 0.69314718056f);
#endif
}

// ---------------------------------------------------------------- kernel 1
// idx < 131072: pack A fragment-major. Frag semantics (R0-verified):
//   lane l of tile (r16,kk) holds A[r16*16 + (l&15)][kk*32 + (l>>4)*8 .. +8]
// else: convert T row-major with chunk XOR swizzle c^(r&7) (byte ^ (r&7)<<4).
__global__ void convert_pack(const float* __restrict__ a,
                             const float* __restrict__ t,
                             ushort* __restrict__ oa,
                             ushort* __restrict__ ot) {
    int idx = blockIdx.x * 256 + threadIdx.x;          // 0 .. 262143
    if (idx < 131072) {
        int l = idx & 63, tile = idx >> 6;
        int kk = tile & 3, r16 = tile >> 2;
        int row = r16 * 16 + (l & 15);
        int k0  = kk * 32 + (l >> 4) * 8;
        const float4* s4 = reinterpret_cast<const float4*>(a + row * 128 + k0);
        float4 f0 = s4[0], f1 = s4[1];
        uint4 o;
        o.x = f2bf(f0.x) | ((unsigned)f2bf(f0.y) << 16);
        o.y = f2bf(f0.z) | ((unsigned)f2bf(f0.w) << 16);
        o.z = f2bf(f1.x) | ((unsigned)f2bf(f1.y) << 16);
        o.w = f2bf(f1.z) | ((unsigned)f2bf(f1.w) << 16);
        *reinterpret_cast<uint4*>(oa + idx * 8) = o;
    } else {
        int loc = idx - 131072;
        int r = loc >> 4, c = loc & 15;
        const float4* s4 = reinterpret_cast<const float4*>(t + r * 128 + c * 8);
        float4 f0 = s4[0], f1 = s4[1];
        uint4 o;
        o.x = f2bf(f0.x) | ((unsigned)f2bf(f0.y) << 16);
        o.y = f2bf(f0.z) | ((unsigned)f2bf(f0.w) << 16);
        o.z = f2bf(f1.x) | ((unsigned)f2bf(f1.y) << 16);
        o.w = f2bf(f1.z) | ((unsigned)f2bf(f1.w) << 16);
        *reinterpret_cast<uint4*>(ot + r * 128 + ((c ^ (r & 7)) << 3)) = o;
    }
}

// ---------------------------------------------------------------- kernel 2
// 128x128 output tile, 4 waves (2x2), K=128 one shot. B staged to 32 KiB LDS
// via global_load_lds; A-frags loaded coalesced global->reg BEFORE the
// barrier (latency hidden under B staging). One barrier per block, 4096
// blocks for TLP (~3 blocks/CU).
__global__ void __launch_bounds__(256)
gemm_exp(const ushort* __restrict__ Ap, const ushort* __restrict__ Tb,
         const float* __restrict__ temps,
         float* __restrict__ Pi, float* __restrict__ Pj) {
    __shared__ ushort ldsB[128 * 128];                 // 32 KiB
    const int bi = blockIdx.x, bj = blockIdx.y;
    const int tid = threadIdx.x;
    const int wave = tid >> 6, lane = tid & 63;
    const int wr = wave >> 1, wc = wave & 1;
    const int krow = lane >> 4, lcol = lane & 15;

    // stage B tile (contiguous 32 KiB, pre-swizzled)
    const ushort* gB = Tb + bj * 16384;
#pragma unroll
    for (int i = 0; i < 8; ++i) {
        int c = wave * 512 + i * 64;                   // wave-uniform chunk base
        GLD16(gB + (c + lane) * 8, &ldsB[c * 8]);
    }

    // A fragments: coalesced 1 KiB wave-loads, frag-major layout
    bf16x8 af[4][4];
    const ushort* gA = Ap + ((bi * 8 + wr * 4) * 4 * 64 + lane) * 8;
#pragma unroll
    for (int m = 0; m < 4; ++m)
#pragma unroll
        for (int kk = 0; kk < 4; ++kk)
            af[m][kk] = *reinterpret_cast<const bf16x8*>(gA + (m * 4 + kk) * 512);

    const float sc2 = __expf(temps[0]) * 1.44269504f;  // exp(temp)*log2(e)
    __builtin_amdgcn_sched_barrier(0);                 // keep loads above barrier
    __syncthreads();

    f32x4 acc[4][4];
#pragma unroll
    for (int m = 0; m < 4; ++m)
#pragma unroll
        for (int n = 0; n < 4; ++n)
            acc[m][n] = (f32x4){0.f, 0.f, 0.f, 0.f};

#pragma unroll
    for (int kk = 0; kk < 4; ++kk) {
        const int k0 = kk * 32 + krow * 8;
        bf16x8 bf[4];
#pragma unroll
        for (int n = 0; n < 4; ++n) {
            int rb = wc * 64 + n * 16 + lcol;
            bf[n] = *reinterpret_cast<const bf16x8*>(
                &ldsB[rb * 128 + (k0 ^ ((rb & 7) << 3))]);
        }
#pragma unroll
        for (int m = 0; m < 4; ++m)
#pragma unroll
            for (int n = 0; n < 4; ++n)
                acc[m][n] = __builtin_amdgcn_mfma_f32_16x16x32_bf16(af[m][kk], bf[n], acc[m][n], 0, 0, 0);
    }

    // ---- epilogue: exp2, row/col partial sums ----
    float rsum[4][4];
    float csum[4] = {0.f, 0.f, 0.f, 0.f};
#pragma unroll
    for (int m = 0; m < 4; ++m)
#pragma unroll
        for (int j = 0; j < 4; ++j) rsum[m][j] = 0.f;

#pragma unroll
    for (int m = 0; m < 4; ++m)
#pragma unroll
        for (int n = 0; n < 4; ++n)
#pragma unroll
            for (int j = 0; j < 4; ++j) {
                float v = fast_exp2(acc[m][n][j] * sc2);
                rsum[m][j] += v;
                csum[n] += v;
            }

    // row sums: reduce over lcol (lanes 0..15 of each krow group)
#pragma unroll
    for (int m = 0; m < 4; ++m)
#pragma unroll
        for (int j = 0; j < 4; ++j) {
            float v = rsum[m][j];
            v += __shfl_xor(v, 1); v += __shfl_xor(v, 2);
            v += __shfl_xor(v, 4); v += __shfl_xor(v, 8);
            if (lcol == 0) {
                int row = bi * 128 + wr * 64 + m * 16 + krow * 4 + j;
                Pi[row * 128 + bj * 2 + wc] = v;
            }
        }
    // col sums: reduce across krow groups
#pragma unroll
    for (int n = 0; n < 4; ++n) {
        float v = csum[n];
        v += __shfl_xor(v, 16); v += __shfl_xor(v, 32);
        if (lane < 16) {
            int col = bj * 128 + wc * 64 + n * 16 + lane;
            Pj[col * 128 + bi * 2 + wr] = v;
        }
    }
}

// ---------------------------------------------------------------- kernel 3
// One wave per row, 4 rows/block; partials transposed so reads coalesce.
__global__ void finalize_rows(const float* __restrict__ a, const float* __restrict__ t,
                              const float* __restrict__ temps,
                              const float* __restrict__ Pi, const float* __restrict__ Pj,
                              float* __restrict__ loss) {
    const int r = blockIdx.x * 4 + (threadIdx.x >> 6);
    const int l = threadIdx.x & 63;
    const float sc = __expf(temps[0]);
    float deni = Pi[r * 128 + l] + Pi[r * 128 + 64 + l];
    float denj = Pj[r * 128 + l] + Pj[r * 128 + 64 + l];
    float dotp = a[r * 128 + l] * t[r * 128 + l]
               + a[r * 128 + 64 + l] * t[r * 128 + 64 + l];
#pragma unroll
    for (int m = 1; m < 64; m <<= 1) {
        deni += __shfl_xor(deni, m);
        denj += __shfl_xor(denj, m);
        dotp += __shfl_xor(dotp, m);
    }
    if (l == 0) {
        float diag = __expf(sc * dotp);
        float di = fmaxf(deni - diag, 1e-20f);
        float dj = fmaxf(denj - diag, 1e-20f);
        loss[r] = -sc * dotp + 0.5f * (__logf(di) + __logf(dj));
    }
}

// ---------------------------------------------------------------- kernel 4
__global__ void reduce_loss(const float* __restrict__ loss, float* __restrict__ out) {
    __shared__ float wsum[16];
    const int tid = threadIdx.x;   // 1024
    float s = 0.f;
#pragma unroll
    for (int i = 0; i < 8; ++i) s += loss[tid + i * 1024];
#pragma unroll
    for (int m = 1; m < 64; m <<= 1) s += __shfl_xor(s, m);
    if ((tid & 63) == 0) wsum[tid >> 6] = s;
    __syncthreads();
    if (tid == 0) {
        float acc = 0.f;
#pragma unroll
        for (int w = 0; w < 16; ++w) acc += wsum[w];
        out[0] = acc * (1.0f / 8192.0f);
    }
}

extern "C" void kernel_launch(void* const* d_in, const int* in_sizes, int n_in,
                              void* d_out, int out_size, void* d_ws, size_t ws_size,
                              hipStream_t stream) {
    const float* a     = (const float*)d_in[0];
    const float* t     = (const float*)d_in[1];
    const float* temps = (const float*)d_in[2];
    float* out = (float*)d_out;

    char* ws = (char*)d_ws;
    ushort* Ap  = (ushort*)(ws);
    ushort* Tb  = (ushort*)(ws + (2u << 20));
    float*  Pi  = (float*)(ws + (4u << 20));
    float*  Pj  = (float*)(ws + (8u << 20));
    float*  los = (float*)(ws + (12u << 20));

    convert_pack<<<1024, 256, 0, stream>>>(a, t, Ap, Tb);
    gemm_exp<<<dim3(64, 64), 256, 0, stream>>>(Ap, Tb, temps, Pi, Pj);
    finalize_rows<<<2048, 256, 0, stream>>>(a, t, temps, Pi, Pj, los);
    reduce_loss<<<1, 1024, 0, stream>>>(los, out);
}